// Round 5
// baseline (56.878 us; speedup 1.0000x reference)
//
#include <hip/hip_runtime.h>

// Problem constants (fixed by setup_inputs)
#define K   19
#define C   256
#define HF  64
#define WF  128
#define HW  (HF * WF)
#define BB  4
#define HL  512
#define WL  1024

// f32 near-tie threshold: our f32 distance error bound is < ~5e-4 and the np
// reference's own f32 error is similar; pixels whose top-2 f32 gap < TAU get
// an exact f64 recompute of the candidates (rare; exact == np proven in R1).
#define TAU 0.015f

// ---- workspace layout (floats unless noted) ----
// [0)      ct map0: [C][K] transposed centroids (4864 f32)
// [4864)   ct map1
// [9728)   c2f map0 [19], [9747) c2f map1 [19]
// byte 39072: c2d map0 [19 f64], then c2d map1 [19 f64]   (8B aligned)
#define WS_CT1   4864
#define WS_C2F0  9728
#define WS_C2F1  9747
#define WS_C2D_BYTE 39072
#define WS_NEED  (WS_C2D_BYTE + 2 * K * 8)

// ---------- setup: transpose centroids to [C][K] + exact ||c||^2 ----------
__global__ __launch_bounds__(256) void centroid_setup_kernel(
    const float* __restrict__ cent0,   // map 0 centroids (centroid_target)
    const float* __restrict__ cent1,   // map 1 centroids (centroid_s2t)
    float* __restrict__ ws)
{
    __shared__ double c2p[K][8];
    const int map = blockIdx.x;
    const float* __restrict__ cent = (map == 0) ? cent0 : cent1;
    float* __restrict__ ct  = ws + map * WS_CT1;
    float* __restrict__ c2f = ws + (map == 0 ? WS_C2F0 : WS_C2F1);
    double* __restrict__ c2d = (double*)((char*)ws + WS_C2D_BYTE) + map * K;

    const int tid = threadIdx.x;
    for (int idx = tid; idx < K * C; idx += 256) {
        int k = idx >> 8, c = idx & (C - 1);
        ct[c * K + k] = cent[idx];               // coalesced read, strided write
    }
    if (tid < K * 8) {
        const int k = tid >> 3, sl = tid & 7;
        const float* cp = cent + k * C + sl * 32;
        double s = 0.0;
        #pragma unroll
        for (int j = 0; j < 32; ++j) { double v = (double)cp[j]; s = fma(v, v, s); }
        c2p[k][sl] = s;
    }
    __syncthreads();
    if (tid < K) {
        double s = 0.0;
        #pragma unroll
        for (int j = 0; j < 8; ++j) s += c2p[tid][j];
        c2d[tid] = s;
        c2f[tid] = (float)s;
    }
}

// ---------- main: 512 thr = 8 waves, 64 pixels, wave wv = channels [wv*32,+32) ----------
// c-outer / k-inner: per channel the 19 centroid values are 19 CONSECUTIVE
// dwords of the [C][K] table -> streaming scalar loads with short dependency
// distance, massive line reuse across the 32 resident waves.
__global__ __launch_bounds__(512, 8) void centroid_mask_kernel(
    const float* __restrict__ feat0,
    const float* __restrict__ feat1,
    const float* __restrict__ ws,      // transposed centroids + c2 tables
    int* __restrict__ out)
{
    __shared__ float part[8 * K * 64];   // [wv][k][pix], pix stride 1: conflict-free

    const int map = blockIdx.y;
    const float* __restrict__ feat = (map == 0) ? feat0 : feat1;
    const float* __restrict__ ctm  = ws + map * WS_CT1;

    const int tid  = threadIdx.x;
    const int lane = tid & 63;
    const int wv   = __builtin_amdgcn_readfirstlane(tid >> 6);   // 0..7, uniform

    const int p  = blockIdx.x * 64 + lane;     // pixel in [0, 32768)
    const int hw = p & (HW - 1);
    const int b  = p >> 13;
    const int cbase = wv * 32;

    // preload this wave's 32 feature channels for pixel = lane
    const float* __restrict__ fp = feat + (size_t)b * C * HW + (size_t)cbase * HW + hw;
    float f[32];
    #pragma unroll
    for (int i = 0; i < 32; ++i) f[i] = fp[(size_t)i * HW];

    float acc[K];
    #pragma unroll
    for (int k = 0; k < K; ++k) acc[k] = 0.f;

    const float* __restrict__ ct = ctm + cbase * K;   // wave-uniform base
    #pragma unroll
    for (int c = 0; c < 32; ++c) {
        const float fc = f[c];
        const float* __restrict__ cc = ct + c * K;    // 19 consecutive dwords
        #pragma unroll
        for (int k = 0; k < K; ++k)
            acc[k] = fmaf(fc, cc[k], acc[k]);         // v_fmac_f32 vgpr, sgpr, vgpr
    }

    float* __restrict__ pw = &part[(wv * K) * 64 + lane];
    #pragma unroll
    for (int k = 0; k < K; ++k) pw[k * 64] = acc[k];
    __syncthreads();

    // ---- epilogue: wave 0, lane = pixel ----
    if (tid < 64) {
        const float* __restrict__ c2f = ws + (map == 0 ? WS_C2F0 : WS_C2F1);
        const double* __restrict__ c2d = (const double*)((const char*)ws + WS_C2D_BYTE) + map * K;

        const int pix = tid;
        float d[K];
        #pragma unroll
        for (int k = 0; k < K; ++k) {
            float s = 0.f;
            #pragma unroll
            for (int w8 = 0; w8 < 8; ++w8)
                s += part[(w8 * K + k) * 64 + pix];
            d[k] = c2f[k] - 2.0f * s;
        }
        int best = 0; float m1 = d[0];
        #pragma unroll
        for (int k = 1; k < K; ++k) if (d[k] < m1) { m1 = d[k]; best = k; }

        unsigned cmask = 0u;
        #pragma unroll
        for (int k = 0; k < K; ++k) if (d[k] - m1 < TAU) cmask |= (1u << k);

        if (cmask & (cmask - 1)) {   // rare near-tie: exact f64 over candidates
            const float* __restrict__ fcol = feat + (size_t)b * C * HW + hw;
            const float* __restrict__ ctc  = ctm;     // [C][K]
            double bd = 1e300; int bi = 0;
            for (int k = 0; k < K; ++k) {
                if ((cmask >> k) & 1) {
                    double s = 0.0;
                    for (int c = 0; c < C; ++c)
                        s = fma((double)fcol[(size_t)c * HW], (double)ctc[c * K + k], s);
                    double dk = c2d[k] - 2.0 * s;
                    if (dk < bd) { bd = dk; bi = k; }   // strict <, ascending k
                }
            }
            best = bi;
        }

        const int w = hw & (WF - 1);
        const int h = hw >> 7;
        int4 v = make_int4(best, best, best, best);
        int* __restrict__ ob = out + (size_t)map * (BB * HL * WL)
                                   + (size_t)b * (HL * WL)
                                   + (size_t)(h * 8) * WL + (size_t)(w * 8);
        #pragma unroll
        for (int r = 0; r < 8; ++r) {
            *(int4*)(ob + (size_t)r * WL)     = v;
            *(int4*)(ob + (size_t)r * WL + 4) = v;
        }
    }
}

// ---------- safety net: R4 kernel (no workspace), used only if ws too small ----------
__global__ __launch_bounds__(512, 8) void centroid_mask_kernel_nows(
    const float* __restrict__ feat0, const float* __restrict__ feat1,
    const float* __restrict__ cent0, const float* __restrict__ cent1,
    int* __restrict__ out)
{
    __shared__ float  part[8 * K * 64];
    __shared__ double c2p[K][8];
    __shared__ double sc2d[K];
    __shared__ float  sc2f[K];
    const int map = blockIdx.y;
    const float* __restrict__ feat = (map == 0) ? feat0 : feat1;
    const float* __restrict__ cent = (map == 0) ? cent0 : cent1;
    const int tid = threadIdx.x, lane = tid & 63;
    const int wv = __builtin_amdgcn_readfirstlane(tid >> 6);
    if (tid < K * 8) {
        const int k = tid >> 3, sl = tid & 7;
        const float* cp = cent + k * C + sl * 32;
        double s = 0.0;
        #pragma unroll
        for (int j = 0; j < 32; ++j) { double v = (double)cp[j]; s = fma(v, v, s); }
        c2p[k][sl] = s;
    }
    const int p = blockIdx.x * 64 + lane;
    const int hw = p & (HW - 1), b = p >> 13, cbase = wv * 32;
    const float* __restrict__ fp = feat + (size_t)b * C * HW + (size_t)cbase * HW + hw;
    float f[32];
    #pragma unroll
    for (int i = 0; i < 32; ++i) f[i] = fp[(size_t)i * HW];
    float* __restrict__ pw = &part[(wv * K) * 64 + lane];
    #pragma unroll
    for (int k = 0; k < K; ++k) {
        const float* __restrict__ ck = cent + (size_t)k * C + cbase;
        float a0 = 0.f, a1 = 0.f, a2 = 0.f, a3 = 0.f;
        #pragma unroll
        for (int j = 0; j < 8; ++j) {
            a0 = fmaf(f[4*j+0], ck[4*j+0], a0);
            a1 = fmaf(f[4*j+1], ck[4*j+1], a1);
            a2 = fmaf(f[4*j+2], ck[4*j+2], a2);
            a3 = fmaf(f[4*j+3], ck[4*j+3], a3);
        }
        pw[k * 64] = (a0 + a1) + (a2 + a3);
    }
    __syncthreads();
    if (tid < K) {
        double s = 0.0;
        #pragma unroll
        for (int j = 0; j < 8; ++j) s += c2p[tid][j];
        sc2d[tid] = s; sc2f[tid] = (float)s;
    }
    __syncthreads();
    if (tid < 64) {
        const int pix = tid;
        float d[K];
        #pragma unroll
        for (int k = 0; k < K; ++k) {
            float s = 0.f;
            #pragma unroll
            for (int w8 = 0; w8 < 8; ++w8) s += part[(w8 * K + k) * 64 + pix];
            d[k] = sc2f[k] - 2.0f * s;
        }
        int best = 0; float m1 = d[0];
        #pragma unroll
        for (int k = 1; k < K; ++k) if (d[k] < m1) { m1 = d[k]; best = k; }
        unsigned cmask = 0u;
        #pragma unroll
        for (int k = 0; k < K; ++k) if (d[k] - m1 < TAU) cmask |= (1u << k);
        if (cmask & (cmask - 1)) {
            const float* __restrict__ fcol = feat + (size_t)b * C * HW + hw;
            double bd = 1e300; int bi = 0;
            for (int k = 0; k < K; ++k) if ((cmask >> k) & 1) {
                const float* __restrict__ ck = cent + (size_t)k * C;
                double s = 0.0;
                for (int c = 0; c < C; ++c)
                    s = fma((double)fcol[(size_t)c * HW], (double)ck[c], s);
                double dk = sc2d[k] - 2.0 * s;
                if (dk < bd) { bd = dk; bi = k; }
            }
            best = bi;
        }
        const int w = hw & (WF - 1), h = hw >> 7;
        int4 v = make_int4(best, best, best, best);
        int* __restrict__ ob = out + (size_t)map * (BB * HL * WL) + (size_t)b * (HL * WL)
                                   + (size_t)(h * 8) * WL + (size_t)(w * 8);
        #pragma unroll
        for (int r = 0; r < 8; ++r) {
            *(int4*)(ob + (size_t)r * WL)     = v;
            *(int4*)(ob + (size_t)r * WL + 4) = v;
        }
    }
}

extern "C" void kernel_launch(void* const* d_in, const int* in_sizes, int n_in,
                              void* d_out, int out_size, void* d_ws, size_t ws_size,
                              hipStream_t stream) {
    const float* feature_s2t     = (const float*)d_in[0];
    const float* feature_target  = (const float*)d_in[1];
    const float* centroid_s2t    = (const float*)d_in[4];
    const float* centroid_target = (const float*)d_in[5];
    int* out = (int*)d_out;

    if (ws_size >= (size_t)WS_NEED) {
        float* ws = (float*)d_ws;
        hipLaunchKernelGGL(centroid_setup_kernel, dim3(2), dim3(256), 0, stream,
                           centroid_target, centroid_s2t, ws);
        hipLaunchKernelGGL(centroid_mask_kernel, dim3(512, 2), dim3(512), 0, stream,
                           feature_s2t, feature_target, ws, out);
    } else {
        hipLaunchKernelGGL(centroid_mask_kernel_nows, dim3(512, 2), dim3(512), 0, stream,
                           feature_s2t, feature_target,
                           centroid_target, centroid_s2t, out);
    }
}

// Round 6
// 42.194 us; speedup vs baseline: 1.3480x; 1.3480x over previous
//
#include <hip/hip_runtime.h>

// Problem constants (fixed by setup_inputs)
#define K   19
#define C   256
#define HF  64
#define WF  128
#define HW  (HF * WF)
#define BB  4
#define HL  512
#define WL  1024

// f32 near-tie threshold: f32 distance error bound here is < ~1e-3;
// pixels whose top-2 f32 gap < TAU get an exact f64 recompute (rare).
#define TAU 0.015f

// Block = 512 threads = 8 waves, 64 pixels (lane = pixel). Wave wv covers
// channels [wv*32, wv*32+32). KEY CHANGE vs R4/R5: __launch_bounds__(512, 4)
// (VGPR cap 128, not 64) so the 32-channel feature preload actually LIVES in
// VGPRs — all 32 global loads in flight per wave (deep MLP) — instead of the
// compiler re-issuing loads inside the FMA loop at 32 VGPRs (R4/R5 profile:
// VGPR_Count=32, VALUBusy ~20%, latency-bound).
__global__ __launch_bounds__(512, 4) void centroid_mask_kernel(
    const float* __restrict__ feat0,   // feature_s2t
    const float* __restrict__ feat1,   // feature_target
    const float* __restrict__ cent0,   // centroids for map 0 (centroid_target)
    const float* __restrict__ cent1,   // centroids for map 1 (centroid_s2t)
    int* __restrict__ out)             // [2][BB][HL][WL] int32
{
    __shared__ float  part[8 * K * 64];  // [wv][k][pix], pix stride 1: conflict-free
    __shared__ double c2p[K][8];         // exact ||c||^2 partials
    __shared__ double sc2d[K];           // exact ||c||^2 (f64)
    __shared__ float  sc2f[K];           // rounded-exact ||c||^2 (f32)

    const int map = blockIdx.y;
    const float* __restrict__ feat = (map == 0) ? feat0 : feat1;
    const float* __restrict__ cent = (map == 0) ? cent0 : cent1;

    const int tid  = threadIdx.x;
    const int lane = tid & 63;
    const int wv   = __builtin_amdgcn_readfirstlane(tid >> 6);   // 0..7, uniform

    // ---- exact ||c_k||^2 partials (f64), 152 threads, overlaps with preload ----
    if (tid < K * 8) {
        const int k = tid >> 3, sl = tid & 7;
        const float* cp = cent + k * C + sl * 32;
        double s = 0.0;
        #pragma unroll
        for (int j = 0; j < 32; ++j) { double v = (double)cp[j]; s = fma(v, v, s); }
        c2p[k][sl] = s;
    }

    // ---- preload this wave's 32 feature channels for pixel = lane ----
    const int p  = blockIdx.x * 64 + lane;     // pixel in [0, 32768)
    const int hw = p & (HW - 1);
    const int b  = p >> 13;
    const int cbase = wv * 32;

    const float* __restrict__ fp = feat + (size_t)b * C * HW + (size_t)cbase * HW + hw;
    float f[32];
    #pragma unroll
    for (int i = 0; i < 32; ++i) f[i] = fp[(size_t)i * HW];
    // Pin: all 32 loads issue HERE, before the FMA loop (no sinking/remat).
    __builtin_amdgcn_sched_barrier(0);

    // k-outer: per k, cent[k][cbase..cbase+32) = 32 consecutive dwords at a
    // wave-uniform address -> 2x s_load_dwordx16; 64 FMA-issue cycles per wait.
    float* __restrict__ pw = &part[(wv * K) * 64 + lane];
    #pragma unroll
    for (int k = 0; k < K; ++k) {
        const float* __restrict__ ck = cent + (size_t)k * C + cbase;
        float a0 = 0.f, a1 = 0.f, a2 = 0.f, a3 = 0.f;
        #pragma unroll
        for (int j = 0; j < 8; ++j) {
            a0 = fmaf(f[4*j+0], ck[4*j+0], a0);
            a1 = fmaf(f[4*j+1], ck[4*j+1], a1);
            a2 = fmaf(f[4*j+2], ck[4*j+2], a2);
            a3 = fmaf(f[4*j+3], ck[4*j+3], a3);
        }
        pw[k * 64] = (a0 + a1) + (a2 + a3);   // ds_write_b32, lane-contiguous
    }
    __syncthreads();

    if (tid < K) {
        double s = 0.0;
        #pragma unroll
        for (int j = 0; j < 8; ++j) s += c2p[tid][j];
        sc2d[tid] = s;
        sc2f[tid] = (float)s;
    }
    __syncthreads();

    // ---- epilogue: wave 0, lane = pixel ----
    if (tid < 64) {
        const int pix = tid;
        float d[K];
        #pragma unroll
        for (int k = 0; k < K; ++k) {
            float s = 0.f;
            #pragma unroll
            for (int w8 = 0; w8 < 8; ++w8)
                s += part[(w8 * K + k) * 64 + pix];
            d[k] = sc2f[k] - 2.0f * s;
        }
        int best = 0; float m1 = d[0];
        #pragma unroll
        for (int k = 1; k < K; ++k) if (d[k] < m1) { m1 = d[k]; best = k; }

        // near-tie candidates within TAU of the f32 min
        unsigned cmask = 0u;
        #pragma unroll
        for (int k = 0; k < K; ++k) if (d[k] - m1 < TAU) cmask |= (1u << k);

        if (cmask & (cmask - 1)) {   // rare: exact f64 recompute of candidates
            const float* __restrict__ fcol = feat + (size_t)b * C * HW + hw;
            double bd = 1e300; int bi = 0;
            for (int k = 0; k < K; ++k) {
                if ((cmask >> k) & 1) {
                    const float* __restrict__ ck = cent + (size_t)k * C;
                    double s = 0.0;
                    for (int c = 0; c < C; ++c)
                        s = fma((double)fcol[(size_t)c * HW], (double)ck[c], s);
                    double dk = sc2d[k] - 2.0 * s;
                    if (dk < bd) { bd = dk; bi = k; }   // strict <, ascending k
                }
            }
            best = bi;
        }

        // write the 8x8 nearest-upsampled block
        const int w = hw & (WF - 1);
        const int h = hw >> 7;
        int4 v = make_int4(best, best, best, best);
        int* __restrict__ ob = out + (size_t)map * (BB * HL * WL)
                                   + (size_t)b * (HL * WL)
                                   + (size_t)(h * 8) * WL + (size_t)(w * 8);
        #pragma unroll
        for (int r = 0; r < 8; ++r) {
            *(int4*)(ob + (size_t)r * WL)     = v;
            *(int4*)(ob + (size_t)r * WL + 4) = v;
        }
    }
}

extern "C" void kernel_launch(void* const* d_in, const int* in_sizes, int n_in,
                              void* d_out, int out_size, void* d_ws, size_t ws_size,
                              hipStream_t stream) {
    const float* feature_s2t     = (const float*)d_in[0];
    const float* feature_target  = (const float*)d_in[1];
    // d_in[2], d_in[3]: labels — only shapes matter, unused
    const float* centroid_s2t    = (const float*)d_in[4];
    const float* centroid_target = (const float*)d_in[5];
    int* out = (int*)d_out;

    dim3 grid(32768 / 64, 2);   // (512, 2) -> 1024 blocks
    dim3 block(512);
    hipLaunchKernelGGL(centroid_mask_kernel, grid, block, 0, stream,
                       feature_s2t, feature_target,
                       centroid_target, centroid_s2t, out);
}